// Round 10
// baseline (36.544 us; speedup 1.0000x reference)
//
#include <hip/hip_runtime.h>

#define BATCH 4
#define NPTS 4096
#define SCONST 0.72134752f   // 0.5*log2(e)
#define CHUNK_TILES 16       // cloud tiles per block chunk
#define CHUNK_PTS   512      // 32 * CHUNK_TILES
#define NJC 8

typedef __attribute__((ext_vector_type(8))) short short8;
typedef __attribute__((ext_vector_type(16))) float f32x16;
typedef unsigned int uint32;

__device__ __forceinline__ unsigned short bf16rn(float x) {
    uint32 u = __float_as_uint(x);
    uint32 r = (u + 0x7FFFu + ((u >> 16) & 1u)) >> 16;
    return (unsigned short)r;
}
__device__ __forceinline__ float bf16tof(unsigned short h) {
    return __uint_as_float(((uint32)h) << 16);
}
__device__ __forceinline__ float m3(float a, float b, float c) {
    return fminf(fminf(a, b), c);    // fuses to v_min3_f32
}
// VALU-only exp2 (10 full-rate ops, rel err ~1e-8): offloads the trans pipe.
__device__ __forceinline__ float pexp2(float x) {
    x = fmaxf(x, -48.0f);
    const float n = __builtin_rintf(x);      // v_rndne_f32
    const float f = x - n;                   // [-0.5, 0.5]
    float p = fmaf(f, 0.00133335581f, 0.00961812910f);
    p = fmaf(f, p, 0.0555041087f);
    p = fmaf(f, p, 0.240226507f);
    p = fmaf(f, p, 0.693147182f);
    p = fmaf(f, p, 1.0f);
    return ldexpf(p, (int)n);                // v_ldexp_f32
}

// K=16 slot pattern (11 used), A=cloud rows, B=query cols:
//  k0-2: ch.qh   k3-5: cl.qh   k6-8: ch.ql   k9-10: bias_h,bias_l x 1.0
// Same half->k assumption on both operands so any HW k-permutation cancels.
// Bias rides in A; C-operand is zero.
__global__ __launch_bounds__(512, 8) void chamfer_main(
    const float* __restrict__ pc1, const float* __restrict__ pc2,
    const float* __restrict__ pc1w,
    float* __restrict__ dsum, float* __restrict__ dmin, float* __restrict__ out)
{
    const int blk  = blockIdx.x;
    const int dirb = blk & 7;             // 8 (dir,b) combos -> XCD L2 affinity
    const int dir  = dirb >> 2, b = dirb & 3;
    const int rest = blk >> 3;
    const int qb   = rest & 15;           // 16 query-blocks of 256 queries
    const int jc   = rest >> 4;           // 8 cloud chunks of 512 points
    const int tid  = threadIdx.x, l = tid & 63, w = tid >> 6;
    const int col  = l & 31, hi = l >> 5;

    if (blk == 0 && tid == 0) out[0] = 0.0f;   // finalize is stream-ordered after

    __shared__ short8 ldsD[CHUNK_TILES * 64];  // 16KB density A-chunk
    __shared__ short8 ldsT[CHUNK_TILES * 64];  // 16KB distance A-chunk

    const size_t cbase = (size_t)b * 3 * NPTS;

    // ---- in-block pack: thread tid packs cloud point (tile=tid>>5,row=tid&31) ----
    {
        const int p  = jc * CHUNK_PTS + tid;
        const int t_ = tid >> 5, r_ = tid & 31;
        const float* srcD = dir ? pc1  : pc2;
        const float* srcT = dir ? pc1w : pc2;
        const float x = srcD[cbase + p], y = srcD[cbase + NPTS + p],
                    z = srcD[cbase + 2 * NPTS + p];
        const float u = srcT[cbase + p], v = srcT[cbase + NPTS + p],
                    q = srcT[cbase + 2 * NPTS + p];
        const float nD = -SCONST * (x * x + y * y + z * z);
        const float nT = u * u + v * v + q * q;

        unsigned short hx = bf16rn(x), hy = bf16rn(y), hz = bf16rn(z);
        unsigned short lx = bf16rn(x - bf16tof(hx)), ly = bf16rn(y - bf16tof(hy)),
                       lz = bf16rn(z - bf16tof(hz));
        unsigned short bh = bf16rn(nD), bl = bf16rn(nD - bf16tof(bh));
        short8 f0 = (short8)0, f1 = (short8)0;
        f0[0]=(short)hx; f0[1]=(short)hy; f0[2]=(short)hz;
        f0[3]=(short)lx; f0[4]=(short)ly; f0[5]=(short)lz;
        f0[6]=(short)hx; f0[7]=(short)hy;
        f1[0]=(short)hz; f1[1]=(short)bh; f1[2]=(short)bl;
        ldsD[t_ * 64 + r_]      = f0;
        ldsD[t_ * 64 + 32 + r_] = f1;

        hx = bf16rn(u); hy = bf16rn(v); hz = bf16rn(q);
        lx = bf16rn(u - bf16tof(hx)); ly = bf16rn(v - bf16tof(hy));
        lz = bf16rn(q - bf16tof(hz));
        bh = bf16rn(nT); bl = bf16rn(nT - bf16tof(bh));
        short8 g0 = (short8)0, g1 = (short8)0;
        g0[0]=(short)hx; g0[1]=(short)hy; g0[2]=(short)hz;
        g0[3]=(short)lx; g0[4]=(short)ly; g0[5]=(short)lz;
        g0[6]=(short)hx; g0[7]=(short)hy;
        g1[0]=(short)hz; g1[1]=(short)bh; g1[2]=(short)bl;
        ldsT[t_ * 64 + r_]      = g0;
        ldsT[t_ * 64 + 32 + r_] = g1;
    }

    // ---- query B-fragments (scales baked in: dens *= 2s, dist *= -2) ----
    const float* qdens = dir ? pc2 : pc1;
    const float* qdist = dir ? pc2 : pc1w;
    const size_t qbase = (size_t)b * 3 * NPTS;
    const int qi = (qb * 8 + w) * 32 + col;

    const float s2 = 2.0f * SCONST;
    float dx = qdens[qbase + qi] * s2, dy = qdens[qbase + NPTS + qi] * s2,
          dz = qdens[qbase + 2 * NPTS + qi] * s2;
    float tx = qdist[qbase + qi] * -2.0f, ty = qdist[qbase + NPTS + qi] * -2.0f,
          tz = qdist[qbase + 2 * NPTS + qi] * -2.0f;
    const unsigned short dhx = bf16rn(dx), dhy = bf16rn(dy), dhz = bf16rn(dz);
    const unsigned short dlx = bf16rn(dx - bf16tof(dhx)), dly = bf16rn(dy - bf16tof(dhy)),
                         dlz = bf16rn(dz - bf16tof(dhz));
    const unsigned short thx = bf16rn(tx), thy = bf16rn(ty), thz = bf16rn(tz);
    const unsigned short tlx = bf16rn(tx - bf16tof(thx)), tly = bf16rn(ty - bf16tof(thy)),
                         tlz = bf16rn(tz - bf16tof(thz));
    const short ONE = (short)0x3F80;     // bf16 1.0

    short8 Bd = (short8)0, Bt = (short8)0;
    if (hi == 0) {
        Bd[0]=(short)dhx; Bd[1]=(short)dhy; Bd[2]=(short)dhz;
        Bd[3]=(short)dhx; Bd[4]=(short)dhy; Bd[5]=(short)dhz;
        Bd[6]=(short)dlx; Bd[7]=(short)dly;
        Bt[0]=(short)thx; Bt[1]=(short)thy; Bt[2]=(short)thz;
        Bt[3]=(short)thx; Bt[4]=(short)thy; Bt[5]=(short)thz;
        Bt[6]=(short)tlx; Bt[7]=(short)tly;
    } else {
        Bd[0]=(short)dlz; Bd[1]=ONE; Bd[2]=ONE;
        Bt[0]=(short)tlz; Bt[1]=ONE; Bt[2]=ONE;
    }
    __syncthreads();

    const f32x16 zc = {0.f,0.f,0.f,0.f,0.f,0.f,0.f,0.f,
                       0.f,0.f,0.f,0.f,0.f,0.f,0.f,0.f};
    float sm = 0.0f;
    float mn = 3.4e38f;

    #pragma unroll 2
    for (int t = 0; t < CHUNK_TILES; ++t) {
        const short8 Ad  = ldsD[t * 64 + l];
        const short8 At2 = ldsT[t * 64 + l];
        // issue both MFMAs before either epilogue (overlap MFMA latency)
        f32x16 ad = __builtin_amdgcn_mfma_f32_32x32x16_bf16(Ad,  Bd, zc, 0, 0, 0);
        f32x16 at = __builtin_amdgcn_mfma_f32_32x32x16_bf16(At2, Bt, zc, 0, 0, 0);

        // density: 10 values on the trans pipe, 6 on the VALU pipe (pexp2)
        float e0 = __builtin_amdgcn_exp2f(ad[0]) + __builtin_amdgcn_exp2f(ad[1]);
        float p0 = pexp2(ad[10]) + pexp2(ad[11]);
        float e1 = __builtin_amdgcn_exp2f(ad[2]) + __builtin_amdgcn_exp2f(ad[3]);
        float p1 = pexp2(ad[12]) + pexp2(ad[13]);
        float e2 = __builtin_amdgcn_exp2f(ad[4]) + __builtin_amdgcn_exp2f(ad[5]);
        float p2 = pexp2(ad[14]) + pexp2(ad[15]);
        float e3 = __builtin_amdgcn_exp2f(ad[6]) + __builtin_amdgcn_exp2f(ad[7]);
        float e4 = __builtin_amdgcn_exp2f(ad[8]) + __builtin_amdgcn_exp2f(ad[9]);
        sm += ((e0 + e1) + (e2 + e3)) + (e4 + (p0 + p1) + p2);

        float n0 = m3(at[0],  at[1],  at[2]);
        float n1 = m3(at[3],  at[4],  at[5]);
        float n2 = m3(at[6],  at[7],  at[8]);
        float n3 = m3(at[9],  at[10], at[11]);
        float n4 = m3(at[12], at[13], at[14]);
        float n5 = m3(n0, n1, n2);
        float n6 = m3(n3, n4, at[15]);
        mn = m3(n5, n6, mn);
    }

    // lanes l and l^32 hold the two row-halves of the same query column
    sm += __shfl_xor(sm, 32);
    mn = fminf(mn, __shfl_xor(mn, 32));

    if (l < 32) {
        const int o = ((jc << 3) | dirb) * NPTS + qi;   // per-chunk slot: no atomics
        dsum[o] = sm;
        dmin[o] = mn;
    }
}

// ---- finalize: combine 8 chunk-partials, mask * relu(min + |q|^2 - eps), mean ----
__global__ __launch_bounds__(512) void finalize_kernel(
    const float* __restrict__ pc1, const float* __restrict__ pc2,
    const float* __restrict__ pc1w, const float* __restrict__ dsum,
    const float* __restrict__ dmin, float* __restrict__ out)
{
    const int gid = blockIdx.x * 512 + threadIdx.x;   // 32768
    const int dirb = gid >> 12, i = gid & (NPTS - 1);
    const int dir = dirb >> 2, b = dirb & 3;
    const size_t qbase = (size_t)b * 3 * NPTS;

    float s = 0.0f, mnv = 3.4e38f;
    #pragma unroll
    for (int jc = 0; jc < NJC; ++jc) {
        const int o = ((jc << 3) | dirb) * NPTS + i;
        s += dsum[o];
        mnv = fminf(mnv, dmin[o]);
    }

    const float* qdens = dir ? pc2 : pc1;
    const float* qdist = dir ? pc2 : pc1w;
    const float ax = qdens[qbase + i], ay = qdens[qbase + NPTS + i],
                az = qdens[qbase + 2 * NPTS + i];
    const float wx = qdist[qbase + i], wy = qdist[qbase + NPTS + i],
                wz = qdist[qbase + 2 * NPTS + i];
    const float q0  = -SCONST * (ax * ax + ay * ay + az * az);
    const float qw2 = wx * wx + wy * wy + wz * wz;

    const float dens = s * __builtin_amdgcn_exp2f(q0);
    const float d2   = mnv + qw2;
    const float thresh = 0.005f * 2.5f * (float)NPTS;   // 51.2
    float c = (dens > thresh) ? fmaxf(d2 - 0.01f, 0.0f) : 0.0f;

    const int l = threadIdx.x & 63, w = threadIdx.x >> 6;
    #pragma unroll
    for (int off = 32; off > 0; off >>= 1) c += __shfl_down(c, off);
    __shared__ float red[8];
    if (l == 0) red[w] = c;
    __syncthreads();
    if (threadIdx.x == 0) {
        float tsum = 0.f;
        #pragma unroll
        for (int k = 0; k < 8; ++k) tsum += red[k];
        atomicAdd(out, tsum * (1.0f / ((float)BATCH * (float)NPTS)));
    }
}

extern "C" void kernel_launch(void* const* d_in, const int* in_sizes, int n_in,
                              void* d_out, int out_size, void* d_ws, size_t ws_size,
                              hipStream_t stream) {
    const float* pc1  = (const float*)d_in[0];
    const float* pc2  = (const float*)d_in[1];
    const float* pc1w = (const float*)d_in[2];
    float* out = (float*)d_out;

    char* ws = (char*)d_ws;
    float* dsum = (float*)ws;                 // 8 jc * 8 dirb * 4096 * 4B = 1 MiB
    float* dmin = (float*)(ws + (1 << 20));   // 1 MiB

    chamfer_main<<<1024, 512, 0, stream>>>(pc1, pc2, pc1w, dsum, dmin, out);
    finalize_kernel<<<64, 512, 0, stream>>>(pc1, pc2, pc1w, dsum, dmin, out);
}

// Round 11
// 26.751 us; speedup vs baseline: 1.3661x; 1.3661x over previous
//
#include <hip/hip_runtime.h>

#define BATCH 4
#define NPTS 4096
#define SCONST 0.72134752f   // 0.5*log2(e)
#define CHUNK_TILES 16       // cloud tiles per block chunk
#define CHUNK_PTS   512      // 32 * CHUNK_TILES
#define NJC 8

typedef __attribute__((ext_vector_type(8))) short short8;
typedef __attribute__((ext_vector_type(16))) float f32x16;
typedef unsigned int uint32;

__device__ __forceinline__ unsigned short bf16rn(float x) {
    uint32 u = __float_as_uint(x);
    uint32 r = (u + 0x7FFFu + ((u >> 16) & 1u)) >> 16;
    return (unsigned short)r;
}
__device__ __forceinline__ float bf16tof(unsigned short h) {
    return __uint_as_float(((uint32)h) << 16);
}
__device__ __forceinline__ float m3(float a, float b, float c) {
    return fminf(fminf(a, b), c);    // fuses to v_min3_f32
}
// 2-op exp2 for x in (-120, 0]: as_float((int)(x*2^23 + 127*2^23)).
// Linear-in-mantissa interpolation of 2^x, rel err <= 6.1% (overestimate).
// Density feeds only the mask (sum > 51.2) -> flips limited to ~6%-boundary
// points; each flip shifts the loss by ~3e-6. v_fma + v_cvt_i32 = 4 issue-cy
// vs ~16 for v_exp_f32 (the R10 regression localized the issue-cost there).
__device__ __forceinline__ float fexp2(float x) {
    float t = fmaf(x, 8388608.0f, 1065353216.0f);
    return __int_as_float((int)t);
}

// K=16 slot pattern (11 used), A=cloud rows, B=query cols:
//  k0-2: ch.qh   k3-5: cl.qh   k6-8: ch.ql   k9-10: bias_h,bias_l x 1.0
// Same half->k assumption on both operands so any HW k-permutation cancels.
// Bias rides in A; C-operand is zero.
__global__ __launch_bounds__(512, 8) void chamfer_main(
    const float* __restrict__ pc1, const float* __restrict__ pc2,
    const float* __restrict__ pc1w,
    float* __restrict__ dsum, float* __restrict__ dmin, float* __restrict__ out)
{
    const int blk  = blockIdx.x;
    const int dirb = blk & 7;             // 8 (dir,b) combos -> XCD L2 affinity
    const int dir  = dirb >> 2, b = dirb & 3;
    const int rest = blk >> 3;
    const int qb   = rest & 15;           // 16 query-blocks of 256 queries
    const int jc   = rest >> 4;           // 8 cloud chunks of 512 points
    const int tid  = threadIdx.x, l = tid & 63, w = tid >> 6;
    const int col  = l & 31, hi = l >> 5;

    if (blk == 0 && tid == 0) out[0] = 0.0f;   // finalize is stream-ordered after

    __shared__ short8 ldsD[CHUNK_TILES * 64];  // 16KB density A-chunk
    __shared__ short8 ldsT[CHUNK_TILES * 64];  // 16KB distance A-chunk

    const size_t cbase = (size_t)b * 3 * NPTS;

    // ---- in-block pack: thread tid packs cloud point (tile=tid>>5,row=tid&31) ----
    {
        const int p  = jc * CHUNK_PTS + tid;
        const int t_ = tid >> 5, r_ = tid & 31;
        const float* srcD = dir ? pc1  : pc2;
        const float* srcT = dir ? pc1w : pc2;
        const float x = srcD[cbase + p], y = srcD[cbase + NPTS + p],
                    z = srcD[cbase + 2 * NPTS + p];
        const float u = srcT[cbase + p], v = srcT[cbase + NPTS + p],
                    q = srcT[cbase + 2 * NPTS + p];
        const float nD = -SCONST * (x * x + y * y + z * z);
        const float nT = u * u + v * v + q * q;

        unsigned short hx = bf16rn(x), hy = bf16rn(y), hz = bf16rn(z);
        unsigned short lx = bf16rn(x - bf16tof(hx)), ly = bf16rn(y - bf16tof(hy)),
                       lz = bf16rn(z - bf16tof(hz));
        unsigned short bh = bf16rn(nD), bl = bf16rn(nD - bf16tof(bh));
        short8 f0 = (short8)0, f1 = (short8)0;
        f0[0]=(short)hx; f0[1]=(short)hy; f0[2]=(short)hz;
        f0[3]=(short)lx; f0[4]=(short)ly; f0[5]=(short)lz;
        f0[6]=(short)hx; f0[7]=(short)hy;
        f1[0]=(short)hz; f1[1]=(short)bh; f1[2]=(short)bl;
        ldsD[t_ * 64 + r_]      = f0;
        ldsD[t_ * 64 + 32 + r_] = f1;

        hx = bf16rn(u); hy = bf16rn(v); hz = bf16rn(q);
        lx = bf16rn(u - bf16tof(hx)); ly = bf16rn(v - bf16tof(hy));
        lz = bf16rn(q - bf16tof(hz));
        bh = bf16rn(nT); bl = bf16rn(nT - bf16tof(bh));
        short8 g0 = (short8)0, g1 = (short8)0;
        g0[0]=(short)hx; g0[1]=(short)hy; g0[2]=(short)hz;
        g0[3]=(short)lx; g0[4]=(short)ly; g0[5]=(short)lz;
        g0[6]=(short)hx; g0[7]=(short)hy;
        g1[0]=(short)hz; g1[1]=(short)bh; g1[2]=(short)bl;
        ldsT[t_ * 64 + r_]      = g0;
        ldsT[t_ * 64 + 32 + r_] = g1;
    }

    // ---- query B-fragments (scales baked in: dens *= 2s, dist *= -2) ----
    const float* qdens = dir ? pc2 : pc1;
    const float* qdist = dir ? pc2 : pc1w;
    const size_t qbase = (size_t)b * 3 * NPTS;
    const int qi = (qb * 8 + w) * 32 + col;

    const float s2 = 2.0f * SCONST;
    float dx = qdens[qbase + qi] * s2, dy = qdens[qbase + NPTS + qi] * s2,
          dz = qdens[qbase + 2 * NPTS + qi] * s2;
    float tx = qdist[qbase + qi] * -2.0f, ty = qdist[qbase + NPTS + qi] * -2.0f,
          tz = qdist[qbase + 2 * NPTS + qi] * -2.0f;
    const unsigned short dhx = bf16rn(dx), dhy = bf16rn(dy), dhz = bf16rn(dz);
    const unsigned short dlx = bf16rn(dx - bf16tof(dhx)), dly = bf16rn(dy - bf16tof(dhy)),
                         dlz = bf16rn(dz - bf16tof(dhz));
    const unsigned short thx = bf16rn(tx), thy = bf16rn(ty), thz = bf16rn(tz);
    const unsigned short tlx = bf16rn(tx - bf16tof(thx)), tly = bf16rn(ty - bf16tof(thy)),
                         tlz = bf16rn(tz - bf16tof(thz));
    const short ONE = (short)0x3F80;     // bf16 1.0

    short8 Bd = (short8)0, Bt = (short8)0;
    if (hi == 0) {
        Bd[0]=(short)dhx; Bd[1]=(short)dhy; Bd[2]=(short)dhz;
        Bd[3]=(short)dhx; Bd[4]=(short)dhy; Bd[5]=(short)dhz;
        Bd[6]=(short)dlx; Bd[7]=(short)dly;
        Bt[0]=(short)thx; Bt[1]=(short)thy; Bt[2]=(short)thz;
        Bt[3]=(short)thx; Bt[4]=(short)thy; Bt[5]=(short)thz;
        Bt[6]=(short)tlx; Bt[7]=(short)tly;
    } else {
        Bd[0]=(short)dlz; Bd[1]=ONE; Bd[2]=ONE;
        Bt[0]=(short)tlz; Bt[1]=ONE; Bt[2]=ONE;
    }
    __syncthreads();

    const f32x16 zc = {0.f,0.f,0.f,0.f,0.f,0.f,0.f,0.f,
                       0.f,0.f,0.f,0.f,0.f,0.f,0.f,0.f};
    float sm = 0.0f;
    float mn = 3.4e38f;

    #pragma unroll 2
    for (int t = 0; t < CHUNK_TILES; ++t) {
        const short8 Ad  = ldsD[t * 64 + l];
        const short8 At2 = ldsT[t * 64 + l];
        // issue both MFMAs before either epilogue (overlap MFMA latency)
        f32x16 ad = __builtin_amdgcn_mfma_f32_32x32x16_bf16(Ad,  Bd, zc, 0, 0, 0);
        f32x16 at = __builtin_amdgcn_mfma_f32_32x32x16_bf16(At2, Bt, zc, 0, 0, 0);

        float e0 = fexp2(ad[0])  + fexp2(ad[1]);
        float e1 = fexp2(ad[2])  + fexp2(ad[3]);
        float e2 = fexp2(ad[4])  + fexp2(ad[5]);
        float e3 = fexp2(ad[6])  + fexp2(ad[7]);
        float e4 = fexp2(ad[8])  + fexp2(ad[9]);
        float e5 = fexp2(ad[10]) + fexp2(ad[11]);
        float e6 = fexp2(ad[12]) + fexp2(ad[13]);
        float e7 = fexp2(ad[14]) + fexp2(ad[15]);
        sm += ((e0 + e1) + (e2 + e3)) + ((e4 + e5) + (e6 + e7));

        float n0 = m3(at[0],  at[1],  at[2]);
        float n1 = m3(at[3],  at[4],  at[5]);
        float n2 = m3(at[6],  at[7],  at[8]);
        float n3 = m3(at[9],  at[10], at[11]);
        float n4 = m3(at[12], at[13], at[14]);
        float n5 = m3(n0, n1, n2);
        float n6 = m3(n3, n4, at[15]);
        mn = m3(n5, n6, mn);
    }

    // lanes l and l^32 hold the two row-halves of the same query column
    sm += __shfl_xor(sm, 32);
    mn = fminf(mn, __shfl_xor(mn, 32));

    if (l < 32) {
        const int o = ((jc << 3) | dirb) * NPTS + qi;   // per-chunk slot: no atomics
        dsum[o] = sm;
        dmin[o] = mn;
    }
}

// ---- finalize: combine 8 chunk-partials, mask * relu(min + |q|^2 - eps), mean ----
__global__ __launch_bounds__(512) void finalize_kernel(
    const float* __restrict__ pc1, const float* __restrict__ pc2,
    const float* __restrict__ pc1w, const float* __restrict__ dsum,
    const float* __restrict__ dmin, float* __restrict__ out)
{
    const int gid = blockIdx.x * 512 + threadIdx.x;   // 32768
    const int dirb = gid >> 12, i = gid & (NPTS - 1);
    const int dir = dirb >> 2, b = dirb & 3;
    const size_t qbase = (size_t)b * 3 * NPTS;

    float s = 0.0f, mnv = 3.4e38f;
    #pragma unroll
    for (int jc = 0; jc < NJC; ++jc) {
        const int o = ((jc << 3) | dirb) * NPTS + i;
        s += dsum[o];
        mnv = fminf(mnv, dmin[o]);
    }

    const float* qdens = dir ? pc2 : pc1;
    const float* qdist = dir ? pc2 : pc1w;
    const float ax = qdens[qbase + i], ay = qdens[qbase + NPTS + i],
                az = qdens[qbase + 2 * NPTS + i];
    const float wx = qdist[qbase + i], wy = qdist[qbase + NPTS + i],
                wz = qdist[qbase + 2 * NPTS + i];
    const float q0  = -SCONST * (ax * ax + ay * ay + az * az);
    const float qw2 = wx * wx + wy * wy + wz * wz;

    const float dens = s * __builtin_amdgcn_exp2f(q0);   // exact here
    const float d2   = mnv + qw2;
    const float thresh = 0.005f * 2.5f * (float)NPTS;    // 51.2
    float c = (dens > thresh) ? fmaxf(d2 - 0.01f, 0.0f) : 0.0f;

    const int l = threadIdx.x & 63, w = threadIdx.x >> 6;
    #pragma unroll
    for (int off = 32; off > 0; off >>= 1) c += __shfl_down(c, off);
    __shared__ float red[8];
    if (l == 0) red[w] = c;
    __syncthreads();
    if (threadIdx.x == 0) {
        float tsum = 0.f;
        #pragma unroll
        for (int k = 0; k < 8; ++k) tsum += red[k];
        atomicAdd(out, tsum * (1.0f / ((float)BATCH * (float)NPTS)));
    }
}

extern "C" void kernel_launch(void* const* d_in, const int* in_sizes, int n_in,
                              void* d_out, int out_size, void* d_ws, size_t ws_size,
                              hipStream_t stream) {
    const float* pc1  = (const float*)d_in[0];
    const float* pc2  = (const float*)d_in[1];
    const float* pc1w = (const float*)d_in[2];
    float* out = (float*)d_out;

    char* ws = (char*)d_ws;
    float* dsum = (float*)ws;                 // 8 jc * 8 dirb * 4096 * 4B = 1 MiB
    float* dmin = (float*)(ws + (1 << 20));   // 1 MiB

    chamfer_main<<<1024, 512, 0, stream>>>(pc1, pc2, pc1w, dsum, dmin, out);
    finalize_kernel<<<64, 512, 0, stream>>>(pc1, pc2, pc1w, dsum, dmin, out);
}

// Round 12
// 23.912 us; speedup vs baseline: 1.5282x; 1.1187x over previous
//
#include <hip/hip_runtime.h>

#define BATCH 4
#define NPTS 4096
#define SCONST 0.72134752f   // 0.5*log2(e)
#define CHUNK_TILES 16       // cloud tiles per block chunk
#define CHUNK_PTS   512      // 32 * CHUNK_TILES
#define NJC 8

typedef __attribute__((ext_vector_type(8))) short short8;
typedef __attribute__((ext_vector_type(16))) float f32x16;
typedef unsigned int uint32;

__device__ __forceinline__ unsigned short bf16rn(float x) {
    uint32 u = __float_as_uint(x);
    uint32 r = (u + 0x7FFFu + ((u >> 16) & 1u)) >> 16;
    return (unsigned short)r;
}
__device__ __forceinline__ float bf16tof(unsigned short h) {
    return __uint_as_float(((uint32)h) << 16);
}
__device__ __forceinline__ float m3(float a, float b, float c) {
    return fminf(fminf(a, b), c);    // fuses to v_min3_f32
}

// K=16 slot pattern (11 used), A=cloud rows, B=query cols:
//  k0-2: ch.qh   k3-5: cl.qh   k6-8: ch.ql   k9-10: bias_h,bias_l x 1.0
// Same half->k assumption on both operands so any HW k-permutation cancels.
// Bias rides in A; C-operand is zero.
// R12 experiment: launch_bounds (512,8)->(512,4). The 64-VGPR cap at 8
// waves/EU is suspected to force spills/serialization of the two live
// f32x16 MFMA results (~80-100 VGPR demand). 128-VGPR budget removes that;
// occupancy drops to >=4 waves/EU (16+ waves/CU).
__global__ __launch_bounds__(512, 4) void chamfer_main(
    const float* __restrict__ pc1, const float* __restrict__ pc2,
    const float* __restrict__ pc1w,
    float* __restrict__ dsum, float* __restrict__ dmin, float* __restrict__ out)
{
    const int blk  = blockIdx.x;
    const int dirb = blk & 7;             // 8 (dir,b) combos -> XCD L2 affinity
    const int dir  = dirb >> 2, b = dirb & 3;
    const int rest = blk >> 3;
    const int qb   = rest & 15;           // 16 query-blocks of 256 queries
    const int jc   = rest >> 4;           // 8 cloud chunks of 512 points
    const int tid  = threadIdx.x, l = tid & 63, w = tid >> 6;
    const int col  = l & 31, hi = l >> 5;

    if (blk == 0 && tid == 0) out[0] = 0.0f;   // finalize is stream-ordered after

    __shared__ short8 ldsD[CHUNK_TILES * 64];  // 16KB density A-chunk
    __shared__ short8 ldsT[CHUNK_TILES * 64];  // 16KB distance A-chunk

    const size_t cbase = (size_t)b * 3 * NPTS;

    // ---- in-block pack: thread tid packs cloud point (tile=tid>>5,row=tid&31) ----
    {
        const int p  = jc * CHUNK_PTS + tid;
        const int t_ = tid >> 5, r_ = tid & 31;
        const float* srcD = dir ? pc1  : pc2;
        const float* srcT = dir ? pc1w : pc2;
        const float x = srcD[cbase + p], y = srcD[cbase + NPTS + p],
                    z = srcD[cbase + 2 * NPTS + p];
        const float u = srcT[cbase + p], v = srcT[cbase + NPTS + p],
                    q = srcT[cbase + 2 * NPTS + p];
        const float nD = -SCONST * (x * x + y * y + z * z);
        const float nT = u * u + v * v + q * q;

        unsigned short hx = bf16rn(x), hy = bf16rn(y), hz = bf16rn(z);
        unsigned short lx = bf16rn(x - bf16tof(hx)), ly = bf16rn(y - bf16tof(hy)),
                       lz = bf16rn(z - bf16tof(hz));
        unsigned short bh = bf16rn(nD), bl = bf16rn(nD - bf16tof(bh));
        short8 f0 = (short8)0, f1 = (short8)0;
        f0[0]=(short)hx; f0[1]=(short)hy; f0[2]=(short)hz;
        f0[3]=(short)lx; f0[4]=(short)ly; f0[5]=(short)lz;
        f0[6]=(short)hx; f0[7]=(short)hy;
        f1[0]=(short)hz; f1[1]=(short)bh; f1[2]=(short)bl;
        ldsD[t_ * 64 + r_]      = f0;
        ldsD[t_ * 64 + 32 + r_] = f1;

        hx = bf16rn(u); hy = bf16rn(v); hz = bf16rn(q);
        lx = bf16rn(u - bf16tof(hx)); ly = bf16rn(v - bf16tof(hy));
        lz = bf16rn(q - bf16tof(hz));
        bh = bf16rn(nT); bl = bf16rn(nT - bf16tof(bh));
        short8 g0 = (short8)0, g1 = (short8)0;
        g0[0]=(short)hx; g0[1]=(short)hy; g0[2]=(short)hz;
        g0[3]=(short)lx; g0[4]=(short)ly; g0[5]=(short)lz;
        g0[6]=(short)hx; g0[7]=(short)hy;
        g1[0]=(short)hz; g1[1]=(short)bh; g1[2]=(short)bl;
        ldsT[t_ * 64 + r_]      = g0;
        ldsT[t_ * 64 + 32 + r_] = g1;
    }

    // ---- query B-fragments (scales baked in: dens *= 2s, dist *= -2) ----
    const float* qdens = dir ? pc2 : pc1;
    const float* qdist = dir ? pc2 : pc1w;
    const size_t qbase = (size_t)b * 3 * NPTS;
    const int qi = (qb * 8 + w) * 32 + col;

    const float s2 = 2.0f * SCONST;
    float dx = qdens[qbase + qi] * s2, dy = qdens[qbase + NPTS + qi] * s2,
          dz = qdens[qbase + 2 * NPTS + qi] * s2;
    float tx = qdist[qbase + qi] * -2.0f, ty = qdist[qbase + NPTS + qi] * -2.0f,
          tz = qdist[qbase + 2 * NPTS + qi] * -2.0f;
    const unsigned short dhx = bf16rn(dx), dhy = bf16rn(dy), dhz = bf16rn(dz);
    const unsigned short dlx = bf16rn(dx - bf16tof(dhx)), dly = bf16rn(dy - bf16tof(dhy)),
                         dlz = bf16rn(dz - bf16tof(dhz));
    const unsigned short thx = bf16rn(tx), thy = bf16rn(ty), thz = bf16rn(tz);
    const unsigned short tlx = bf16rn(tx - bf16tof(thx)), tly = bf16rn(ty - bf16tof(thy)),
                         tlz = bf16rn(tz - bf16tof(thz));
    const short ONE = (short)0x3F80;     // bf16 1.0

    short8 Bd = (short8)0, Bt = (short8)0;
    if (hi == 0) {
        Bd[0]=(short)dhx; Bd[1]=(short)dhy; Bd[2]=(short)dhz;
        Bd[3]=(short)dhx; Bd[4]=(short)dhy; Bd[5]=(short)dhz;
        Bd[6]=(short)dlx; Bd[7]=(short)dly;
        Bt[0]=(short)thx; Bt[1]=(short)thy; Bt[2]=(short)thz;
        Bt[3]=(short)thx; Bt[4]=(short)thy; Bt[5]=(short)thz;
        Bt[6]=(short)tlx; Bt[7]=(short)tly;
    } else {
        Bd[0]=(short)dlz; Bd[1]=ONE; Bd[2]=ONE;
        Bt[0]=(short)tlz; Bt[1]=ONE; Bt[2]=ONE;
    }
    __syncthreads();

    const f32x16 zc = {0.f,0.f,0.f,0.f,0.f,0.f,0.f,0.f,
                       0.f,0.f,0.f,0.f,0.f,0.f,0.f,0.f};
    float sm = 0.0f;
    float mn = 3.4e38f;

    #pragma unroll 2
    for (int t = 0; t < CHUNK_TILES; ++t) {
        const short8 Ad  = ldsD[t * 64 + l];
        const short8 At2 = ldsT[t * 64 + l];
        // issue both MFMAs before either epilogue (overlap MFMA latency)
        f32x16 ad = __builtin_amdgcn_mfma_f32_32x32x16_bf16(Ad,  Bd, zc, 0, 0, 0);
        f32x16 at = __builtin_amdgcn_mfma_f32_32x32x16_bf16(At2, Bt, zc, 0, 0, 0);

        float e0 = __builtin_amdgcn_exp2f(ad[0])  + __builtin_amdgcn_exp2f(ad[1]);
        float e1 = __builtin_amdgcn_exp2f(ad[2])  + __builtin_amdgcn_exp2f(ad[3]);
        float e2 = __builtin_amdgcn_exp2f(ad[4])  + __builtin_amdgcn_exp2f(ad[5]);
        float e3 = __builtin_amdgcn_exp2f(ad[6])  + __builtin_amdgcn_exp2f(ad[7]);
        float e4 = __builtin_amdgcn_exp2f(ad[8])  + __builtin_amdgcn_exp2f(ad[9]);
        float e5 = __builtin_amdgcn_exp2f(ad[10]) + __builtin_amdgcn_exp2f(ad[11]);
        float e6 = __builtin_amdgcn_exp2f(ad[12]) + __builtin_amdgcn_exp2f(ad[13]);
        float e7 = __builtin_amdgcn_exp2f(ad[14]) + __builtin_amdgcn_exp2f(ad[15]);
        sm += ((e0 + e1) + (e2 + e3)) + ((e4 + e5) + (e6 + e7));

        float n0 = m3(at[0],  at[1],  at[2]);
        float n1 = m3(at[3],  at[4],  at[5]);
        float n2 = m3(at[6],  at[7],  at[8]);
        float n3 = m3(at[9],  at[10], at[11]);
        float n4 = m3(at[12], at[13], at[14]);
        float n5 = m3(n0, n1, n2);
        float n6 = m3(n3, n4, at[15]);
        mn = m3(n5, n6, mn);
    }

    // lanes l and l^32 hold the two row-halves of the same query column
    sm += __shfl_xor(sm, 32);
    mn = fminf(mn, __shfl_xor(mn, 32));

    if (l < 32) {
        const int o = ((jc << 3) | dirb) * NPTS + qi;   // per-chunk slot: no atomics
        dsum[o] = sm;
        dmin[o] = mn;
    }
}

// ---- finalize: combine 8 chunk-partials, mask * relu(min + |q|^2 - eps), mean ----
__global__ __launch_bounds__(512) void finalize_kernel(
    const float* __restrict__ pc1, const float* __restrict__ pc2,
    const float* __restrict__ pc1w, const float* __restrict__ dsum,
    const float* __restrict__ dmin, float* __restrict__ out)
{
    const int gid = blockIdx.x * 512 + threadIdx.x;   // 32768
    const int dirb = gid >> 12, i = gid & (NPTS - 1);
    const int dir = dirb >> 2, b = dirb & 3;
    const size_t qbase = (size_t)b * 3 * NPTS;

    float s = 0.0f, mnv = 3.4e38f;
    #pragma unroll
    for (int jc = 0; jc < NJC; ++jc) {
        const int o = ((jc << 3) | dirb) * NPTS + i;
        s += dsum[o];
        mnv = fminf(mnv, dmin[o]);
    }

    const float* qdens = dir ? pc2 : pc1;
    const float* qdist = dir ? pc2 : pc1w;
    const float ax = qdens[qbase + i], ay = qdens[qbase + NPTS + i],
                az = qdens[qbase + 2 * NPTS + i];
    const float wx = qdist[qbase + i], wy = qdist[qbase + NPTS + i],
                wz = qdist[qbase + 2 * NPTS + i];
    const float q0  = -SCONST * (ax * ax + ay * ay + az * az);
    const float qw2 = wx * wx + wy * wy + wz * wz;

    const float dens = s * __builtin_amdgcn_exp2f(q0);
    const float d2   = mnv + qw2;
    const float thresh = 0.005f * 2.5f * (float)NPTS;   // 51.2
    float c = (dens > thresh) ? fmaxf(d2 - 0.01f, 0.0f) : 0.0f;

    const int l = threadIdx.x & 63, w = threadIdx.x >> 6;
    #pragma unroll
    for (int off = 32; off > 0; off >>= 1) c += __shfl_down(c, off);
    __shared__ float red[8];
    if (l == 0) red[w] = c;
    __syncthreads();
    if (threadIdx.x == 0) {
        float tsum = 0.f;
        #pragma unroll
        for (int k = 0; k < 8; ++k) tsum += red[k];
        atomicAdd(out, tsum * (1.0f / ((float)BATCH * (float)NPTS)));
    }
}

extern "C" void kernel_launch(void* const* d_in, const int* in_sizes, int n_in,
                              void* d_out, int out_size, void* d_ws, size_t ws_size,
                              hipStream_t stream) {
    const float* pc1  = (const float*)d_in[0];
    const float* pc2  = (const float*)d_in[1];
    const float* pc1w = (const float*)d_in[2];
    float* out = (float*)d_out;

    char* ws = (char*)d_ws;
    float* dsum = (float*)ws;                 // 8 jc * 8 dirb * 4096 * 4B = 1 MiB
    float* dmin = (float*)(ws + (1 << 20));   // 1 MiB

    chamfer_main<<<1024, 512, 0, stream>>>(pc1, pc2, pc1w, dsum, dmin, out);
    finalize_kernel<<<64, 512, 0, stream>>>(pc1, pc2, pc1w, dsum, dmin, out);
}